// Round 1
// baseline (73.216 us; speedup 1.0000x reference)
//
#include <hip/hip_runtime.h>

// Coulomb pair-energy reduction.
// inputs: 0 coords f32[100000*3], 1 pairs i32[6400000*2], 2 box f32[9],
//         3 charges f32[100000], 4 prefac f32[1], 5 cutoff f32[1], 6 do_shift i32[1]
// output: f32[1] = prefac * sum_masked(q_i q_j (1/r - shift))

constexpr int TPB = 256;

// ws layout:
//   [0, 8)       double accumulator
//   [16, 16+20*4) float params: boxInv(9), c2, shift, box(9)
//   [256, ...)   packed atoms float4 {x,y,z,q}
constexpr size_t WS_PAR_OFF   = 16;
constexpr size_t WS_ATOMS_OFF = 256;

__global__ void setup_kernel(const float* __restrict__ box,
                             const float* __restrict__ cutoff_p,
                             const int* __restrict__ do_shift_p,
                             double* __restrict__ acc,
                             float* __restrict__ par) {
    if (threadIdx.x == 0 && blockIdx.x == 0) {
        *acc = 0.0;
        float b00 = box[0], b01 = box[1], b02 = box[2];
        float b10 = box[3], b11 = box[4], b12 = box[5];
        float b20 = box[6], b21 = box[7], b22 = box[8];
        float det = b00*(b11*b22 - b12*b21)
                  - b01*(b10*b22 - b12*b20)
                  + b02*(b10*b21 - b11*b20);
        float id = 1.0f / det;
        // boxInv (row-major), inverse via adjugate
        par[0] =  (b11*b22 - b12*b21) * id;   // i00
        par[1] = -(b01*b22 - b02*b21) * id;   // i01
        par[2] =  (b01*b12 - b02*b11) * id;   // i02
        par[3] = -(b10*b22 - b12*b20) * id;   // i10
        par[4] =  (b00*b22 - b02*b20) * id;   // i11
        par[5] = -(b00*b12 - b02*b10) * id;   // i12
        par[6] =  (b10*b21 - b11*b20) * id;   // i20
        par[7] = -(b00*b21 - b01*b20) * id;   // i21
        par[8] =  (b00*b11 - b01*b10) * id;   // i22
        float cut = *cutoff_p;
        par[9]  = cut * cut;
        par[10] = (*do_shift_p) ? (1.0f / cut) : 0.0f;
        par[11] = b00; par[12] = b01; par[13] = b02;
        par[14] = b10; par[15] = b11; par[16] = b12;
        par[17] = b20; par[18] = b21; par[19] = b22;
    }
}

__global__ void pack_atoms_kernel(const float* __restrict__ coords,
                                  const float* __restrict__ charges,
                                  float4* __restrict__ atoms, int n) {
    int i = blockIdx.x * blockDim.x + threadIdx.x;
    if (i < n) {
        atoms[i] = make_float4(coords[3*i], coords[3*i + 1], coords[3*i + 2],
                               charges[i]);
    }
}

__device__ __forceinline__ float pair_e(float4 ai, float4 aj, const float* P) {
    float dx = ai.x - aj.x, dy = ai.y - aj.y, dz = ai.z - aj.z;
    // ds = dr @ boxInv   (row-vector x matrix)
    float sx = dx*P[0] + dy*P[3] + dz*P[6];
    float sy = dx*P[1] + dy*P[4] + dz*P[7];
    float sz = dx*P[2] + dy*P[5] + dz*P[8];
    sx -= floorf(sx + 0.5f);
    sy -= floorf(sy + 0.5f);
    sz -= floorf(sz + 0.5f);
    // drPBC = ds @ box
    float px = sx*P[11] + sy*P[14] + sz*P[17];
    float py = sx*P[12] + sy*P[15] + sz*P[18];
    float pz = sx*P[13] + sy*P[16] + sz*P[19];
    float r2 = px*px + py*py + pz*pz;
    float rinv = rsqrtf(r2);
    float e = ai.w * aj.w * (rinv - P[10]);
    return (r2 <= P[9]) ? e : 0.0f;
}

template<bool PACKED>
__global__ __launch_bounds__(TPB)
void coulomb_main(const int4* __restrict__ pairs4, int npairs4, int npairs,
                  const int2* __restrict__ pairs2,
                  const float4* __restrict__ atoms,
                  const float* __restrict__ coords,
                  const float* __restrict__ charges,
                  const float* __restrict__ par,
                  double* __restrict__ acc) {
    float P[20];
#pragma unroll
    for (int k = 0; k < 20; ++k) P[k] = par[k];  // uniform -> scalar loads

    double lsum = 0.0;
    int tid = blockIdx.x * blockDim.x + threadIdx.x;
    int stride = gridDim.x * blockDim.x;

    for (int p = tid; p < npairs4; p += stride) {
        int4 pr = pairs4[p];
        float4 a0, a1, b0, b1;
        if (PACKED) {
            a0 = atoms[pr.x]; a1 = atoms[pr.y];
            b0 = atoms[pr.z]; b1 = atoms[pr.w];
        } else {
            a0 = make_float4(coords[3*pr.x], coords[3*pr.x+1], coords[3*pr.x+2], charges[pr.x]);
            a1 = make_float4(coords[3*pr.y], coords[3*pr.y+1], coords[3*pr.y+2], charges[pr.y]);
            b0 = make_float4(coords[3*pr.z], coords[3*pr.z+1], coords[3*pr.z+2], charges[pr.z]);
            b1 = make_float4(coords[3*pr.w], coords[3*pr.w+1], coords[3*pr.w+2], charges[pr.w]);
        }
        lsum += (double)pair_e(a0, a1, P);
        lsum += (double)pair_e(b0, b1, P);
    }
    // odd-tail pair (npairs odd), handled by one thread
    if (tid == 0 && (npairs & 1)) {
        int2 pr = pairs2[npairs - 1];
        float4 a0, a1;
        if (PACKED) {
            a0 = atoms[pr.x]; a1 = atoms[pr.y];
        } else {
            a0 = make_float4(coords[3*pr.x], coords[3*pr.x+1], coords[3*pr.x+2], charges[pr.x]);
            a1 = make_float4(coords[3*pr.y], coords[3*pr.y+1], coords[3*pr.y+2], charges[pr.y]);
        }
        lsum += (double)pair_e(a0, a1, P);
    }

    // wave reduce (64 lanes)
#pragma unroll
    for (int off = 32; off > 0; off >>= 1)
        lsum += __shfl_down(lsum, off);

    __shared__ double wsum[TPB / 64];
    int lane = threadIdx.x & 63;
    int wid  = threadIdx.x >> 6;
    if (lane == 0) wsum[wid] = lsum;
    __syncthreads();
    if (threadIdx.x == 0) {
        double s = 0.0;
#pragma unroll
        for (int w = 0; w < TPB / 64; ++w) s += wsum[w];
        atomicAdd(acc, s);
    }
}

__global__ void finalize_kernel(const double* __restrict__ acc,
                                const float* __restrict__ prefac_p,
                                float* __restrict__ out) {
    if (threadIdx.x == 0 && blockIdx.x == 0)
        out[0] = (float)(*acc * (double)(*prefac_p));
}

extern "C" void kernel_launch(void* const* d_in, const int* in_sizes, int n_in,
                              void* d_out, int out_size, void* d_ws, size_t ws_size,
                              hipStream_t stream) {
    const float* coords   = (const float*)d_in[0];
    const int*   pairs    = (const int*)d_in[1];
    const float* box      = (const float*)d_in[2];
    const float* charges  = (const float*)d_in[3];
    const float* prefac   = (const float*)d_in[4];
    const float* cutoff   = (const float*)d_in[5];
    const int*   do_shift = (const int*)d_in[6];
    float* out = (float*)d_out;

    int natoms = in_sizes[0] / 3;
    int npairs = in_sizes[1] / 2;
    int npairs4 = npairs / 2;

    double* acc = (double*)d_ws;
    float*  par = (float*)((char*)d_ws + WS_PAR_OFF);
    float4* atoms = (float4*)((char*)d_ws + WS_ATOMS_OFF);
    bool packed = (ws_size >= WS_ATOMS_OFF + (size_t)natoms * sizeof(float4));

    setup_kernel<<<1, 64, 0, stream>>>(box, cutoff, do_shift, acc, par);

    if (packed) {
        pack_atoms_kernel<<<(natoms + TPB - 1) / TPB, TPB, 0, stream>>>(
            coords, charges, atoms, natoms);
    }

    int blocks = (npairs4 + TPB - 1) / TPB;
    if (blocks > 2048) blocks = 2048;
    if (blocks < 1) blocks = 1;

    if (packed) {
        coulomb_main<true><<<blocks, TPB, 0, stream>>>(
            (const int4*)pairs, npairs4, npairs, (const int2*)pairs,
            atoms, coords, charges, par, acc);
    } else {
        coulomb_main<false><<<blocks, TPB, 0, stream>>>(
            (const int4*)pairs, npairs4, npairs, (const int2*)pairs,
            nullptr, coords, charges, par, acc);
    }

    finalize_kernel<<<1, 64, 0, stream>>>(acc, prefac, out);
}